// Round 9
// baseline (298.372 us; speedup 1.0000x reference)
//
#include <hip/hip_runtime.h>

#define N_EDGES 1048576
#define N_GRAPH 512
#define REG     2560         // per-graph ebuf capacity (mean 2048, wide margin)
#define MAXE    2560
#define PAD     64           // global counter padding (u32) = 256 B
#define CHUNK   2048         // edges per scatter block
#define SBLK    (N_EDGES / CHUNK)

typedef __attribute__((ext_vector_type(4))) float floatx4;
typedef __attribute__((ext_vector_type(2))) float floatx2;
typedef __attribute__((ext_vector_type(4))) int intx4;

// ---------------- preprocessing ----------------
__global__ void zero_kernel(unsigned* __restrict__ p, int n) {
    int i = blockIdx.x * blockDim.x + threadIdx.x;
    if (i < n) p[i] = 0u;
}

// LDS counting-sort scatter: sort 2048 edges by graph locally, write runs
// near-coalesced (consecutive sorted slots -> consecutive global addresses).
__global__ void scatter_kernel(const int* __restrict__ src, const int* __restrict__ dst,
                               unsigned* __restrict__ cnt, unsigned short* __restrict__ ebuf) {
    __shared__ unsigned short sbuf[CHUNK];   // sorted packed edges
    __shared__ unsigned short sg[CHUNK];     // graph id per sorted slot
    __shared__ unsigned lhist[512];
    __shared__ unsigned lscan[512];
    __shared__ unsigned gbase[512];
    const int t = threadIdx.x;
    lhist[t] = 0; lhist[t + 256] = 0;
    __syncthreads();
    const intx4* s4 = (const intx4*)(src + blockIdx.x * CHUNK) + t * 2;
    const intx4* d4 = (const intx4*)(dst + blockIdx.x * CHUNK) + t * 2;
    unsigned short gg[8], pk[8], rr[8];
#pragma unroll
    for (int h = 0; h < 2; ++h) {
        intx4 sv = s4[h], dv = d4[h];
        int ss[4] = {sv.x, sv.y, sv.z, sv.w};
        int dd[4] = {dv.x, dv.y, dv.z, dv.w};
#pragma unroll
        for (int j = 0; j < 4; ++j) {
            unsigned g = ((unsigned)dd[j]) >> 7;
            gg[h * 4 + j] = (unsigned short)g;
            pk[h * 4 + j] = (unsigned short)((ss[j] & 127) | ((dd[j] & 127) << 8));
            rr[h * 4 + j] = (unsigned short)atomicAdd(&lhist[g], 1u);
        }
    }
    __syncthreads();
    // inclusive scan of 512 entries (2 per thread), then exclusive + global base
    unsigned a0 = lhist[t], a1 = lhist[t + 256];
    lscan[t] = a0; lscan[t + 256] = a1;
    __syncthreads();
    for (int d = 1; d < 512; d <<= 1) {
        unsigned v0 = (t >= d) ? lscan[t - d] : 0u;
        unsigned v1 = (t + 256 >= d) ? lscan[t + 256 - d] : 0u;
        __syncthreads();
        lscan[t] += v0; lscan[t + 256] += v1;
        __syncthreads();
    }
    lscan[t] -= a0; lscan[t + 256] -= a1;            // exclusive
    gbase[t]       = a0 ? atomicAdd(&cnt[(size_t)t * PAD], a0)         : 0u;
    gbase[t + 256] = a1 ? atomicAdd(&cnt[(size_t)(t + 256) * PAD], a1) : 0u;
    __syncthreads();
#pragma unroll
    for (int j = 0; j < 8; ++j) {
        unsigned pos = lscan[gg[j]] + rr[j];
        sbuf[pos] = pk[j]; sg[pos] = gg[j];
    }
    __syncthreads();
    for (int i = t; i < CHUNK; i += 256) {
        unsigned g = sg[i];
        unsigned pos = gbase[g] + (i - lscan[g]);
        if (pos < REG) ebuf[(size_t)g * REG + pos] = sbuf[i];
    }
}

// ---------------- GCN matmul phase (register-tiled, writes H into Xio) ----
template<int CIN, int COUT>
__device__ void gcn_matmul(const float* Xin, float* Xio,
                           const float* __restrict__ W, int tid)
{
    constexpr int CL  = COUT / 4;
    constexpr int NPT = 128 / (1024 / CL);
    const int grp = tid / CL, cl = tid % CL;

    float acc[NPT][4];
#pragma unroll
    for (int ni = 0; ni < NPT; ++ni)
#pragma unroll
        for (int j = 0; j < 4; ++j) acc[ni][j] = 0.f;

    for (int k = 0; k < CIN; k += 4) {
        floatx4 xv[NPT];
#pragma unroll
        for (int ni = 0; ni < NPT; ++ni)
            xv[ni] = *(const floatx4*)(Xin + (grp * NPT + ni) * CIN + k);
#pragma unroll
        for (int i = 0; i < 4; ++i) {
            floatx4 wv = *(const floatx4*)(W + (k + i) * COUT + cl * 4);
#pragma unroll
            for (int ni = 0; ni < NPT; ++ni)
#pragma unroll
                for (int j = 0; j < 4; ++j)
                    acc[ni][j] += xv[ni][i] * wv[j];
        }
    }
    __syncthreads();                 // everyone done reading Xin (may alias Xio)
#pragma unroll
    for (int ni = 0; ni < NPT; ++ni) {
        floatx4 v; v[0] = acc[ni][0]; v[1] = acc[ni][1]; v[2] = acc[ni][2]; v[3] = acc[ni][3];
        *(floatx4*)(Xio + (grp * NPT + ni) * COUT + cl * 4) = v;
    }
    __syncthreads();                 // H visible
}

// ---------------- GCN aggregation phase (wide channels, packed edges) ----
// CPT channels/thread, TPN = COUT/CPT threads/node, TOT = 128*TPN threads.
// Per edge: 1 ds_read_b64 (coef,src) + CPT/4 ds_read_b128. Self-term from H.
template<int COUT, int CPT>
__device__ void gcn_agg(float* Xio, const float* __restrict__ Bv,
                        const float* __restrict__ dinv, const int* __restrict__ offs,
                        const float* __restrict__ epack, int tid)
{
    constexpr int TPN = COUT / CPT;
    constexpr int TOT = 128 * TPN;
    constexpr int NV  = CPT / 4;
    float v[NV][4];
    if (tid < TOT) {
        const int n = tid / TPN, cb = (tid % TPN) * CPT;
        float a[NV][4];
#pragma unroll
        for (int q = 0; q < NV; ++q)
#pragma unroll
            for (int j = 0; j < 4; ++j) a[q][j] = 0.f;
        const int o0 = offs[n], o1 = offs[n + 1];
        for (int p = o0; p < o1; ++p) {
            floatx2 e = *(const floatx2*)(epack + 2 * p);
            float cf = e[0];
            int s = (int)__float_as_uint(e[1]);
            const float* hr = Xio + s * COUT + cb;
#pragma unroll
            for (int q = 0; q < NV; ++q) {
                floatx4 h = *(const floatx4*)(hr + q * 4);
#pragma unroll
                for (int j = 0; j < 4; ++j) a[q][j] += h[j] * cf;
            }
        }
        float dn = dinv[n], dnn = dn * dn;
#pragma unroll
        for (int q = 0; q < NV; ++q) {
            floatx4 hs = *(const floatx4*)(Xio + n * COUT + cb + q * 4);
            floatx4 bv = *(const floatx4*)(Bv + cb + q * 4);
#pragma unroll
            for (int j = 0; j < 4; ++j) {
                float t2 = a[q][j] + hs[j] * dnn + bv[j];
                t2 = tanhf(t2);
                v[q][j] = fminf(fmaxf(t2, -1.0f), 1.0f);
            }
        }
    }
    __syncthreads();                 // all H reads done before overwrite
    if (tid < TOT) {
        const int n = tid / TPN, cb = (tid % TPN) * CPT;
#pragma unroll
        for (int q = 0; q < NV; ++q) {
            floatx4 o; o[0] = v[q][0]; o[1] = v[q][1]; o[2] = v[q][2]; o[3] = v[q][3];
            *(floatx4*)(Xio + n * COUT + cb + q * 4) = o;
        }
    }
    __syncthreads();
}

// ---------------- fused per-graph kernel ----------------
__global__ __launch_bounds__(1024, 1) void mega_kernel(
    const float* __restrict__ x,
    const float* __restrict__ W1, const float* __restrict__ b1,
    const float* __restrict__ W2, const float* __restrict__ b2,
    const float* __restrict__ W3, const float* __restrict__ b3,
    const float* __restrict__ W4, const float* __restrict__ b4,
    const float* __restrict__ W5, const float* __restrict__ b5,
    const float* __restrict__ W6, const float* __restrict__ b6,
    const float* __restrict__ Wf1, const float* __restrict__ bf1,
    const float* __restrict__ Wf2, const float* __restrict__ bf2,
    const unsigned* __restrict__ cnt, const unsigned short* __restrict__ ebuf,
    float* __restrict__ out)
{
    __shared__ __align__(16) char pool[162048];
    int*   ldeg = (int*)(pool + 0);                       // int[128]
    int*   offs = (int*)(pool + 512);                     // int[129]
    float* dinv = (float*)(pool + 1040);                  // f32[128]
    float* key  = (float*)(pool + 1552);                  // f32[128]
    unsigned short* ord = (unsigned short*)(pool + 2064); // u16[64]
    float* epack = (float*)(pool + 2304);                 // (coef,src) x 2560 = 20480 B
    float* W5s   = (float*)(pool + 2304);                 // 16 KB tail overlay (epack dead)
    float* X1   = (float*)(pool + 22784);    // 128x128 (64 KB)
    float* X2   = (float*)(pool + 88320);    // 128x64  (32 KB)
    float* X3   = (float*)(pool + 121088);   // 128x32  (16 KB)
    float* X4   = (float*)(pool + 137472);   // 128x32  (16 KB)
    float* SCR  = (float*)(pool + 153856);   // 8 KB phased tail scratch
    float* Zs   = SCR;                 // 16x64
    float* ZMP  = SCR + 1024;          // 16x32
    float* Z896 = SCR;                 // 896 (over dead Zs)
    float* PART = SCR + 1024;          // 8x128 (over dead ZMP)
    float* FC1  = SCR + 896;           // 128
    float* LG   = SCR;                 // 17 (over dead Z896 head)

    const int g   = blockIdx.x;
    const int tid = threadIdx.x;
    int cnt_g = (int)cnt[(size_t)g * PAD];
    if (cnt_g > MAXE) cnt_g = MAXE;
    const unsigned short* eg = ebuf + (size_t)g * REG;

    // ---- load this thread's edges (<=3) into regs ----
    unsigned short ev[3]; int ne = 0;
    for (int e = tid; e < cnt_g; e += 1024) ev[ne++] = eg[e];

    // ---- degree histogram + prefix + dinv ----
    if (tid < 128) ldeg[tid] = 0;
    __syncthreads();
    for (int i = 0; i < ne; ++i) atomicAdd(&ldeg[(ev[i] >> 8) & 127], 1);
    __syncthreads();
    if (tid < 128) offs[tid + 1] = ldeg[tid];
    if (tid == 0)  offs[0] = 0;
    __syncthreads();
    for (int d = 1; d < 128; d <<= 1) {
        int v = 0;
        if (tid < 128 && tid >= d) v = offs[tid + 1 - d];
        __syncthreads();
        if (tid < 128 && tid >= d) offs[tid + 1] += v;
        __syncthreads();
    }
    if (tid < 128) {
        dinv[tid] = 1.0f / sqrtf((float)(1 + ldeg[tid]));  // self-loop + in-degree
        ldeg[tid] = offs[tid];                              // repurpose as cursor
    }
    __syncthreads();
    // ---- scatter into packed edge list (coef, src) ----
    for (int i = 0; i < ne; ++i) {
        int dn_ = (ev[i] >> 8) & 127, sn = ev[i] & 127;
        int p = atomicAdd(&ldeg[dn_], 1);
        floatx2 e; e[0] = dinv[sn] * dinv[dn_]; e[1] = __uint_as_float((unsigned)sn);
        *(floatx2*)(epack + 2 * p) = e;
    }
    // ---- stage x into X1 (layer-1 runs in-place there) ----
    const float* xg = x + (size_t)g * 16384;
    for (int idx = tid; idx < 4096; idx += 1024)
        *(floatx4*)(X1 + idx * 4) = *(const floatx4*)(xg + idx * 4);
    __syncthreads();

    // ---- 4 GCN layers ----
    gcn_matmul<128, 128>(X1, X1, W1, tid);
    gcn_agg<128, 16>(X1, b1, dinv, offs, epack, tid);
    gcn_matmul<128,  64>(X1, X2, W2, tid);
    gcn_agg< 64,  8>(X2, b2, dinv, offs, epack, tid);
    gcn_matmul< 64,  32>(X2, X3, W3, tid);
    gcn_agg< 32,  8>(X3, b3, dinv, offs, epack, tid);
    gcn_matmul< 32,  32>(X3, X4, W4, tid);
    gcn_agg< 32,  8>(X4, b4, dinv, offs, epack, tid);

    // ---- sort key + stage W5 (over dead epack) ----
    if (tid < 128) key[tid] = X4[tid * 32 + 31];
    if (tid < 64)  ord[tid] = (unsigned short)tid;
    __syncthreads();                   // epack fully dead before overwrite
    for (int idx = tid; idx < 4096; idx += 1024) W5s[idx] = W5[idx];
    __syncthreads();
    if (tid < 128) {
        float myk = key[tid];
        int r = 0;
        for (int j = 0; j < 128; ++j) {
            float kj = key[j];
            r += (kj > myk) || (kj == myk && j < tid);
        }
        if (r < 64) ord[r] = (unsigned short)tid;
    }
    __syncthreads();

    // ---- z = relu(Conv1d(1,16,256,256)), float4 ----
    {
        int q = tid >> 6, t = tid & 63;
        int node = ord[t] & 127;
        float z0 = b5[q];
        const float* w5a = W5s + q * 256;
        floatx4 zv = {0.f, 0.f, 0.f, 0.f};
        for (int jj = 0; jj < 32; ++jj) {
            int j = (jj + t) & 31;
            floatx4 pv = *(const floatx4*)(X1 + node * 128 + j * 4);
            floatx4 wv = *(const floatx4*)(w5a + j * 4);
#pragma unroll
            for (int u = 0; u < 4; ++u) zv[u] += pv[u] * wv[u];
        }
        for (int jj = 0; jj < 16; ++jj) {
            int j = (jj + t) & 15;
            floatx4 pv = *(const floatx4*)(X2 + node * 64 + j * 4);
            floatx4 wv = *(const floatx4*)(w5a + 128 + j * 4);
#pragma unroll
            for (int u = 0; u < 4; ++u) zv[u] += pv[u] * wv[u];
        }
        for (int jj = 0; jj < 8; ++jj) {
            int j = (jj + t) & 7;
            floatx4 pv = *(const floatx4*)(X3 + node * 32 + j * 4);
            floatx4 wv = *(const floatx4*)(w5a + 192 + j * 4);
#pragma unroll
            for (int u = 0; u < 4; ++u) zv[u] += pv[u] * wv[u];
        }
        for (int jj = 0; jj < 8; ++jj) {
            int j = (jj + t) & 7;
            floatx4 pv = *(const floatx4*)(X4 + node * 32 + j * 4);
            floatx4 wv = *(const floatx4*)(w5a + 224 + j * 4);
#pragma unroll
            for (int u = 0; u < 4; ++u) zv[u] += pv[u] * wv[u];
        }
        z0 += zv[0] + zv[1] + zv[2] + zv[3];
        Zs[q * 64 + t] = fmaxf(z0, 0.f);
    }
    __syncthreads();
    // ---- maxpool(2,2) ----
    if (tid < 512) {
        int c = tid >> 5, p = tid & 31;
        ZMP[c * 32 + p] = fmaxf(Zs[c * 64 + 2 * p], Zs[c * 64 + 2 * p + 1]);
    }
    __syncthreads();
    // ---- stage W6 (over dead W5s) ----
    for (int idx = tid; idx < 2560; idx += 1024) W5s[idx] = W6[idx];
    __syncthreads();
    // ---- conv1d(16,32,5) VALID + relu ----
    if (tid < 896) {
        int oc = tid / 28, p = tid % 28;
        float s = b6[oc];
#pragma unroll
        for (int i = 0; i < 16; ++i) {
            const float* wrow = W5s + (oc * 16 + i) * 5;
#pragma unroll
            for (int k = 0; k < 5; ++k)
                s += ZMP[i * 32 + p + k] * wrow[k];
        }
        Z896[tid] = fmaxf(s, 0.f);
    }
    __syncthreads();
    // ---- fc1 (896->128), split-K x8 ----
    {
        int f = tid & 127, q = tid >> 7;
        float s = 0.f;
        for (int i = q * 112; i < (q + 1) * 112; ++i)
            s += Z896[i] * Wf1[i * 128 + f];
        PART[q * 128 + f] = s;
    }
    __syncthreads();
    if (tid < 128) {
        float s = bf1[tid];
#pragma unroll
        for (int q = 0; q < 8; ++q) s += PART[q * 128 + tid];
        FC1[tid] = fmaxf(s, 0.f);
    }
    __syncthreads();
    // ---- fc2 (128->10) + log_softmax ----
    if (tid < 10) {
        float s = bf2[tid];
        for (int i = 0; i < 128; ++i) s += FC1[i] * Wf2[i * 10 + tid];
        LG[tid] = s;
    }
    __syncthreads();
    if (tid == 0) {
        float mx = LG[0];
        for (int i = 1; i < 10; ++i) mx = fmaxf(mx, LG[i]);
        float se = 0.f;
        for (int i = 0; i < 10; ++i) se += expf(LG[i] - mx);
        LG[16] = mx + logf(se);
    }
    __syncthreads();
    if (tid < 10)
        out[g * 10 + tid] = LG[tid] - LG[16];
}

extern "C" void kernel_launch(void* const* d_in, const int* in_sizes, int n_in,
                              void* d_out, int out_size, void* d_ws, size_t ws_size,
                              hipStream_t stream) {
    (void)in_sizes; (void)n_in; (void)out_size; (void)ws_size;
    const float* x   = (const float*)d_in[0];
    const float* W1  = (const float*)d_in[1];
    const float* b1  = (const float*)d_in[2];
    const float* W2  = (const float*)d_in[3];
    const float* b2  = (const float*)d_in[4];
    const float* W3  = (const float*)d_in[5];
    const float* b3  = (const float*)d_in[6];
    const float* W4  = (const float*)d_in[7];
    const float* b4  = (const float*)d_in[8];
    const float* W5  = (const float*)d_in[9];
    const float* b5  = (const float*)d_in[10];
    const float* W6  = (const float*)d_in[11];
    const float* b6  = (const float*)d_in[12];
    const float* Wf1 = (const float*)d_in[13];
    const float* bf1 = (const float*)d_in[14];
    const float* Wf2 = (const float*)d_in[15];
    const float* bf2 = (const float*)d_in[16];
    const int* ei  = (const int*)d_in[17];
    const int* src = ei;
    const int* dst = ei + N_EDGES;

    char* ws = (char*)d_ws;
    unsigned* cnt         = (unsigned*)(ws);                  // 512*PAD u32 = 128 KB
    unsigned short* ebuf  = (unsigned short*)(ws + 131072);   // u16[512*REG] = 2.5 MB

    zero_kernel<<<32, 1024, 0, stream>>>(cnt, 512 * PAD);
    scatter_kernel<<<SBLK, 256, 0, stream>>>(src, dst, cnt, ebuf);
    mega_kernel<<<N_GRAPH, 1024, 0, stream>>>(x, W1, b1, W2, b2, W3, b3, W4, b4,
                                              W5, b5, W6, b6, Wf1, bf1, Wf2, bf2,
                                              cnt, ebuf, (float*)d_out);
}

// Round 10
// 279.058 us; speedup vs baseline: 1.0692x; 1.0692x over previous
//
#include <hip/hip_runtime.h>

#define N_EDGES 1048576
#define N_GRAPH 512
#define MAXE    2560
#define CHUNK   2048
#define SBLK    (N_EDGES / CHUNK)   // 512

typedef __attribute__((ext_vector_type(4))) float floatx4;
typedef __attribute__((ext_vector_type(2))) float floatx2;
typedef __attribute__((ext_vector_type(4))) int intx4;

// ---------------- preprocessing: fully local counting sort ----------------
// Block b sorts its 2048 edges by graph, writes them contiguously (coalesced)
// to ebuf[b][0..2048) and one u32 (count<<16)|start per graph to cstab[g][b].
__global__ void scatter_kernel(const int* __restrict__ src, const int* __restrict__ dst,
                               unsigned* __restrict__ cstab, unsigned short* __restrict__ ebuf) {
    __shared__ unsigned short sbuf[CHUNK];
    __shared__ unsigned short sg[CHUNK];
    __shared__ unsigned lhist[512];
    __shared__ unsigned lscan[512];
    const int t = threadIdx.x;
    const int b = blockIdx.x;
    lhist[t] = 0; lhist[t + 256] = 0;
    __syncthreads();
    const intx4* s4 = (const intx4*)(src + b * CHUNK) + t * 2;
    const intx4* d4 = (const intx4*)(dst + b * CHUNK) + t * 2;
    unsigned short gg[8], pk[8], rr[8];
#pragma unroll
    for (int h = 0; h < 2; ++h) {
        intx4 sv = s4[h], dv = d4[h];
        int ss[4] = {sv.x, sv.y, sv.z, sv.w};
        int dd[4] = {dv.x, dv.y, dv.z, dv.w};
#pragma unroll
        for (int j = 0; j < 4; ++j) {
            unsigned g = ((unsigned)dd[j]) >> 7;
            gg[h * 4 + j] = (unsigned short)g;
            pk[h * 4 + j] = (unsigned short)((ss[j] & 127) | ((dd[j] & 127) << 8));
            rr[h * 4 + j] = (unsigned short)atomicAdd(&lhist[g], 1u);
        }
    }
    __syncthreads();
    unsigned a0 = lhist[t], a1 = lhist[t + 256];
    lscan[t] = a0; lscan[t + 256] = a1;
    __syncthreads();
    for (int d = 1; d < 512; d <<= 1) {
        unsigned v0 = (t >= d) ? lscan[t - d] : 0u;
        unsigned v1 = (t + 256 >= d) ? lscan[t + 256 - d] : 0u;
        __syncthreads();
        lscan[t] += v0; lscan[t + 256] += v1;
        __syncthreads();
    }
    lscan[t] -= a0; lscan[t + 256] -= a1;            // exclusive start within block
    cstab[(size_t)t * SBLK + b]         = (a0 << 16) | lscan[t];
    cstab[(size_t)(t + 256) * SBLK + b] = (a1 << 16) | lscan[t + 256];
    __syncthreads();
#pragma unroll
    for (int j = 0; j < 8; ++j) {
        unsigned pos = lscan[gg[j]] + rr[j];
        sbuf[pos] = pk[j]; sg[pos] = gg[j];
    }
    __syncthreads();
    for (int i = t; i < CHUNK; i += 256)             // coalesced u16 writes
        ebuf[(size_t)b * CHUNK + i] = sbuf[i];
    (void)sg;
}

// ---------------- GCN layer (R8-style unified, b64 packed edges) ----------
// CL = COUT/4 channel-lanes, NPT nodes/thread. Matmul acc in regs; H written
// in-place to Xio; aggregation: per edge 1 ds_read_b64 (coef,src) + 1 b128 H
// (half-wave shares node -> contiguous 128 floats -> conflict-free).
template<int CIN, int COUT>
__device__ void gcn_layer(const float* Xin, float* Xio,
                          const float* __restrict__ W, const float* __restrict__ Bv,
                          const float* __restrict__ dinv, const int* __restrict__ offs,
                          const float* __restrict__ epack, int tid)
{
    constexpr int CL  = COUT / 4;
    constexpr int NPT = 128 / (1024 / CL);
    const int grp = tid / CL, cl = tid % CL;

    float acc[NPT][4];
#pragma unroll
    for (int ni = 0; ni < NPT; ++ni)
#pragma unroll
        for (int j = 0; j < 4; ++j) acc[ni][j] = 0.f;

    for (int k = 0; k < CIN; k += 4) {
        floatx4 xv[NPT];
#pragma unroll
        for (int ni = 0; ni < NPT; ++ni)
            xv[ni] = *(const floatx4*)(Xin + (grp * NPT + ni) * CIN + k);
#pragma unroll
        for (int i = 0; i < 4; ++i) {
            floatx4 wv = *(const floatx4*)(W + (k + i) * COUT + cl * 4);
#pragma unroll
            for (int ni = 0; ni < NPT; ++ni)
#pragma unroll
                for (int j = 0; j < 4; ++j)
                    acc[ni][j] += xv[ni][i] * wv[j];
        }
    }
    __syncthreads();                 // done reading Xin (may alias Xio)
#pragma unroll
    for (int ni = 0; ni < NPT; ++ni) {
        floatx4 v; v[0] = acc[ni][0]; v[1] = acc[ni][1]; v[2] = acc[ni][2]; v[3] = acc[ni][3];
        *(floatx4*)(Xio + (grp * NPT + ni) * COUT + cl * 4) = v;
    }
    __syncthreads();                 // H visible

    floatx4 bv = *(const floatx4*)(Bv + cl * 4);
    float vout[NPT][4];
#pragma unroll
    for (int ni = 0; ni < NPT; ++ni) {
        int n = grp * NPT + ni;
        float a[4] = {0.f, 0.f, 0.f, 0.f};
        int o0 = offs[n], o1 = offs[n + 1];
        for (int p = o0; p < o1; ++p) {
            floatx2 e = *(const floatx2*)(epack + 2 * p);
            float cf = e[0];
            int s = (int)__float_as_uint(e[1]);
            floatx4 h = *(const floatx4*)(Xio + s * COUT + cl * 4);
#pragma unroll
            for (int j = 0; j < 4; ++j) a[j] += h[j] * cf;
        }
        float dn = dinv[n], dnn = dn * dn;
#pragma unroll
        for (int j = 0; j < 4; ++j)
            vout[ni][j] = tanhf(a[j] + acc[ni][j] * dnn + bv[j]);
    }
    __syncthreads();                 // all H reads done before overwrite
#pragma unroll
    for (int ni = 0; ni < NPT; ++ni) {
        floatx4 v; v[0] = vout[ni][0]; v[1] = vout[ni][1]; v[2] = vout[ni][2]; v[3] = vout[ni][3];
        *(floatx4*)(Xio + (grp * NPT + ni) * COUT + cl * 4) = v;
    }
    __syncthreads();
}

// ---------------- fused per-graph kernel ----------------
__global__ __launch_bounds__(1024, 1) void mega_kernel(
    const float* __restrict__ x,
    const float* __restrict__ W1, const float* __restrict__ b1,
    const float* __restrict__ W2, const float* __restrict__ b2,
    const float* __restrict__ W3, const float* __restrict__ b3,
    const float* __restrict__ W4, const float* __restrict__ b4,
    const float* __restrict__ W5, const float* __restrict__ b5,
    const float* __restrict__ W6, const float* __restrict__ b6,
    const float* __restrict__ Wf1, const float* __restrict__ bf1,
    const float* __restrict__ Wf2, const float* __restrict__ bf2,
    const unsigned* __restrict__ cstab, const unsigned short* __restrict__ ebuf,
    float* __restrict__ out)
{
    __shared__ __align__(16) char pool[162048];
    int*   ldeg = (int*)(pool + 0);                       // int[128]
    int*   offs = (int*)(pool + 512);                     // int[129]
    float* dinv = (float*)(pool + 1040);                  // f32[128]
    float* key  = (float*)(pool + 1552);                  // f32[128]
    unsigned short* ord = (unsigned short*)(pool + 2064); // u16[64]
    float* epack = (float*)(pool + 2304);                 // (coef,src) x 2560 = 20480 B
    float* W5s   = (float*)(pool + 2304);                 // 16 KB tail overlay (epack dead)
    float* X1   = (float*)(pool + 22784);    // 128x128 (64 KB)
    float* X2   = (float*)(pool + 88320);    // 128x64  (32 KB)
    float* X3   = (float*)(pool + 121088);   // 128x32  (16 KB)
    float* X4   = (float*)(pool + 137472);   // 128x32  (16 KB)
    float* SCR  = (float*)(pool + 153856);   // 8 KB phased tail scratch
    float* Zs   = SCR;                 // 16x64
    float* ZMP  = SCR + 1024;          // 16x32
    float* Z896 = SCR;                 // 896 (over dead Zs)
    float* PART = SCR + 1024;          // 8x128 (over dead ZMP)
    float* FC1  = SCR + 896;           // 128
    float* LG   = SCR;                 // 17 (over dead Z896 head)

    const int g   = blockIdx.x;
    const int tid = threadIdx.x;

    // ---- fetch this thread's (block-bucket) edge run into registers ----
    int myc = 0;
    unsigned short ev[24];
    if (tid < SBLK) {
        unsigned cs = cstab[(size_t)g * SBLK + tid];
        int start = (int)(cs & 0xFFFFu);
        myc = (int)(cs >> 16);
        if (myc > 24) myc = 24;                    // P ~ 1e-11 per run
        const unsigned short* run = ebuf + (size_t)tid * CHUNK + start;
#pragma unroll
        for (int w = 0; w < 24; ++w)
            ev[w] = (w < myc) ? run[w] : (unsigned short)0;
    }

    // ---- degree histogram ----
    if (tid < 128) ldeg[tid] = 0;
    __syncthreads();
#pragma unroll
    for (int w = 0; w < 24; ++w)
        if (w < myc) atomicAdd(&ldeg[(ev[w] >> 8) & 127], 1);
    __syncthreads();
    // ---- single-wave shfl scan over 128 degree counts ----
    if (tid < 64) {
        int v0 = ldeg[2 * tid], v1 = ldeg[2 * tid + 1];
        int s = v0 + v1;
        for (int d = 1; d < 64; d <<= 1) {
            int u = __shfl_up(s, d, 64);
            if (tid >= d) s += u;
        }
        int e1 = s - v1, e2 = s;
        offs[2 * tid + 1] = (e1 < MAXE) ? e1 : MAXE;
        offs[2 * tid + 2] = (e2 < MAXE) ? e2 : MAXE;
        if (tid == 0) offs[0] = 0;
    }
    if (tid >= 128 && tid < 256) {
        int n = tid - 128;
        dinv[n] = 1.0f / sqrtf((float)(1 + ldeg[n]));   // self-loop + in-degree
    }
    __syncthreads();
    if (tid < 128) ldeg[tid] = offs[tid];               // cursor
    __syncthreads();
    // ---- scatter into packed edge list (coef, src) ----
#pragma unroll
    for (int w = 0; w < 24; ++w)
        if (w < myc) {
            int dn_ = (ev[w] >> 8) & 127, sn = ev[w] & 127;
            int p = atomicAdd(&ldeg[dn_], 1);
            if (p < MAXE) {
                floatx2 e; e[0] = dinv[sn] * dinv[dn_]; e[1] = __uint_as_float((unsigned)sn);
                *(floatx2*)(epack + 2 * p) = e;
            }
        }
    // ---- stage x into X1 (layer-1 runs in-place there) ----
    const float* xg = x + (size_t)g * 16384;
    for (int idx = tid; idx < 4096; idx += 1024)
        *(floatx4*)(X1 + idx * 4) = *(const floatx4*)(xg + idx * 4);
    __syncthreads();

    // ---- 4 GCN layers ----
    gcn_layer<128, 128>(X1, X1, W1, b1, dinv, offs, epack, tid);
    gcn_layer<128,  64>(X1, X2, W2, b2, dinv, offs, epack, tid);
    gcn_layer< 64,  32>(X2, X3, W3, b3, dinv, offs, epack, tid);
    gcn_layer< 32,  32>(X3, X4, W4, b4, dinv, offs, epack, tid);

    // ---- sort key + stage W5 (over dead epack) ----
    if (tid < 128) key[tid] = X4[tid * 32 + 31];
    if (tid < 64)  ord[tid] = (unsigned short)tid;
    __syncthreads();                   // epack fully dead before overwrite
    for (int idx = tid; idx < 4096; idx += 1024) W5s[idx] = W5[idx];
    __syncthreads();
    if (tid < 128) {
        float myk = key[tid];
        int r = 0;
        for (int j = 0; j < 128; ++j) {
            float kj = key[j];
            r += (kj > myk) || (kj == myk && j < tid);
        }
        if (r < 64) ord[r] = (unsigned short)tid;
    }
    __syncthreads();

    // ---- z = relu(Conv1d(1,16,256,256)), float4 ----
    {
        int q = tid >> 6, t = tid & 63;
        int node = ord[t] & 127;
        float z0 = b5[q];
        const float* w5a = W5s + q * 256;
        floatx4 zv = {0.f, 0.f, 0.f, 0.f};
        for (int jj = 0; jj < 32; ++jj) {
            int j = (jj + t) & 31;
            floatx4 pv = *(const floatx4*)(X1 + node * 128 + j * 4);
            floatx4 wv = *(const floatx4*)(w5a + j * 4);
#pragma unroll
            for (int u = 0; u < 4; ++u) zv[u] += pv[u] * wv[u];
        }
        for (int jj = 0; jj < 16; ++jj) {
            int j = (jj + t) & 15;
            floatx4 pv = *(const floatx4*)(X2 + node * 64 + j * 4);
            floatx4 wv = *(const floatx4*)(w5a + 128 + j * 4);
#pragma unroll
            for (int u = 0; u < 4; ++u) zv[u] += pv[u] * wv[u];
        }
        for (int jj = 0; jj < 8; ++jj) {
            int j = (jj + t) & 7;
            floatx4 pv = *(const floatx4*)(X3 + node * 32 + j * 4);
            floatx4 wv = *(const floatx4*)(w5a + 192 + j * 4);
#pragma unroll
            for (int u = 0; u < 4; ++u) zv[u] += pv[u] * wv[u];
        }
        for (int jj = 0; jj < 8; ++jj) {
            int j = (jj + t) & 7;
            floatx4 pv = *(const floatx4*)(X4 + node * 32 + j * 4);
            floatx4 wv = *(const floatx4*)(w5a + 224 + j * 4);
#pragma unroll
            for (int u = 0; u < 4; ++u) zv[u] += pv[u] * wv[u];
        }
        z0 += zv[0] + zv[1] + zv[2] + zv[3];
        Zs[q * 64 + t] = fmaxf(z0, 0.f);
    }
    __syncthreads();
    // ---- maxpool(2,2) ----
    if (tid < 512) {
        int c = tid >> 5, p = tid & 31;
        ZMP[c * 32 + p] = fmaxf(Zs[c * 64 + 2 * p], Zs[c * 64 + 2 * p + 1]);
    }
    __syncthreads();
    // ---- stage W6 (over dead W5s) ----
    for (int idx = tid; idx < 2560; idx += 1024) W5s[idx] = W6[idx];
    __syncthreads();
    // ---- conv1d(16,32,5) VALID + relu ----
    if (tid < 896) {
        int oc = tid / 28, p = tid % 28;
        float s = b6[oc];
#pragma unroll
        for (int i = 0; i < 16; ++i) {
            const float* wrow = W5s + (oc * 16 + i) * 5;
#pragma unroll
            for (int k = 0; k < 5; ++k)
                s += ZMP[i * 32 + p + k] * wrow[k];
        }
        Z896[tid] = fmaxf(s, 0.f);
    }
    __syncthreads();
    // ---- fc1 (896->128), split-K x8 ----
    {
        int f = tid & 127, q = tid >> 7;
        float s = 0.f;
        for (int i = q * 112; i < (q + 1) * 112; ++i)
            s += Z896[i] * Wf1[i * 128 + f];
        PART[q * 128 + f] = s;
    }
    __syncthreads();
    if (tid < 128) {
        float s = bf1[tid];
#pragma unroll
        for (int q = 0; q < 8; ++q) s += PART[q * 128 + tid];
        FC1[tid] = fmaxf(s, 0.f);
    }
    __syncthreads();
    // ---- fc2 (128->10) + log_softmax ----
    if (tid < 10) {
        float s = bf2[tid];
        for (int i = 0; i < 128; ++i) s += FC1[i] * Wf2[i * 10 + tid];
        LG[tid] = s;
    }
    __syncthreads();
    if (tid == 0) {
        float mx = LG[0];
        for (int i = 1; i < 10; ++i) mx = fmaxf(mx, LG[i]);
        float se = 0.f;
        for (int i = 0; i < 10; ++i) se += expf(LG[i] - mx);
        LG[16] = mx + logf(se);
    }
    __syncthreads();
    if (tid < 10)
        out[g * 10 + tid] = LG[tid] - LG[16];
}

extern "C" void kernel_launch(void* const* d_in, const int* in_sizes, int n_in,
                              void* d_out, int out_size, void* d_ws, size_t ws_size,
                              hipStream_t stream) {
    (void)in_sizes; (void)n_in; (void)out_size; (void)ws_size;
    const float* x   = (const float*)d_in[0];
    const float* W1  = (const float*)d_in[1];
    const float* b1  = (const float*)d_in[2];
    const float* W2  = (const float*)d_in[3];
    const float* b2  = (const float*)d_in[4];
    const float* W3  = (const float*)d_in[5];
    const float* b3  = (const float*)d_in[6];
    const float* W4  = (const float*)d_in[7];
    const float* b4  = (const float*)d_in[8];
    const float* W5  = (const float*)d_in[9];
    const float* b5  = (const float*)d_in[10];
    const float* W6  = (const float*)d_in[11];
    const float* b6  = (const float*)d_in[12];
    const float* Wf1 = (const float*)d_in[13];
    const float* bf1 = (const float*)d_in[14];
    const float* Wf2 = (const float*)d_in[15];
    const float* bf2 = (const float*)d_in[16];
    const int* ei  = (const int*)d_in[17];
    const int* src = ei;
    const int* dst = ei + N_EDGES;

    char* ws = (char*)d_ws;
    unsigned short* ebuf = (unsigned short*)(ws);             // u16[512*2048] = 2 MB
    unsigned*       cstab = (unsigned*)(ws + 2097152);        // u32[512*512] = 1 MB

    scatter_kernel<<<SBLK, 256, 0, stream>>>(src, dst, cstab, ebuf);
    mega_kernel<<<N_GRAPH, 1024, 0, stream>>>(x, W1, b1, W2, b2, W3, b3, W4, b4,
                                              W5, b5, W6, b6, Wf1, bf1, Wf2, bf2,
                                              cstab, ebuf, (float*)d_out);
}